// Round 1
// 69.264 us; speedup vs baseline: 1.0243x; 1.0243x over previous
//
#include <hip/hip_runtime.h>
#include <math.h>

// Problem constants (from reference)
#define N_PRED 1000
#define M_BOX  2000
#define K_PASS 10
#define C_CLS  80
#define EPS_IOU 1e-7f

#define BLK_T  (K_PASS * 64)   // 640 threads: wave w == pass k
#define IDX_INF 0x7fffffff

// Block = one pred n x all K passes (wave k owns pass k).
// 1000 blocks -> ~3 resident blocks/CU (~7.5 waves/SIMD) for latency hiding
// and dynamic balancing of the triangular scan workload.
// Scan: ascending 128-box chunks (2 boxes/lane, 4 independent loads in
// flight). First match found via ballot+ctz (scalar pipe), wave-uniform
// break at the first chunk containing a hit == exact "first match" semantics.
// Coverage is contiguous from 0, so no w.h.p. caveat: if nothing matched in
// [0, roundup(n+1,64)+pad) we keep scanning to M (rare).
// IoU>0.5 test is divide-free: inter > 0.5*den, den in ref rounding order
// (identical expression to the previously verified absmax==0 kernel).
__global__ __launch_bounds__(BLK_T)
void ue_cls_kernel(const float* __restrict__ pred,    // [N,6]
                   const float* __restrict__ dpreds,  // [K,M,6]
                   const float* __restrict__ dconfs,  // [K,M,C]
                   float* __restrict__ out)           // [N]
{
    const int n    = blockIdx.x;
    const int k    = threadIdx.x >> 6;
    const int lane = threadIdx.x & 63;

    __shared__ float s_u[K_PASS];
    __shared__ float s_m[K_PASS];

    // pred box: wave-uniform -> scalar loads
    const float* pr = pred + n * 6;
    const float px1 = pr[0], py1 = pr[1], px2 = pr[2], py2 = pr[3];
    const float a1  = (px2 - px1) * (py2 - py1);

    const int kbase = k * M_BOX;                 // fits int easily
    const float2* dp2 = (const float2*)dpreds;   // row = 3 float2, 8B aligned

    // bounded schedule: L covers box index n (the jittered copy of pred n),
    // rounded so every chunk read stays < M without guards (L <= 1024).
    const int L = ((n >> 6) + 1) << 6;
    int first = IDX_INF;
    int c0 = 0;
    for (; c0 < L; c0 += 128) {
        const int iA = (kbase + c0 + lane) * 3;
        const int iB = iA + 64 * 3;
        const float2 aA = dp2[iA];
        const float2 bA = dp2[iA + 1];
        const float2 aB = dp2[iB];
        const float2 bB = dp2[iB + 1];

        const float areaA = (bA.x - aA.x) * (bA.y - aA.y);
        const float ix1A = fmaxf(px1, aA.x);
        const float iy1A = fmaxf(py1, aA.y);
        const float ix2A = fminf(px2, bA.x);
        const float iy2A = fminf(py2, bA.y);
        const float interA = fmaxf(ix2A - ix1A, 0.0f) * fmaxf(iy2A - iy1A, 0.0f);
        const float denA = a1 + areaA - interA + EPS_IOU;

        const float areaB = (bB.x - aB.x) * (bB.y - aB.y);
        const float ix1B = fmaxf(px1, aB.x);
        const float iy1B = fmaxf(py1, aB.y);
        const float ix2B = fminf(px2, bB.x);
        const float iy2B = fminf(py2, bB.y);
        const float interB = fmaxf(ix2B - ix1B, 0.0f) * fmaxf(iy2B - iy1B, 0.0f);
        const float denB = a1 + areaB - interB + EPS_IOU;

        const unsigned long long hitA = __ballot(interA > 0.5f * denA);
        const unsigned long long hitB = __ballot(interB > 0.5f * denB);
        if (hitA) { first = c0 + __builtin_ctzll(hitA); break; }
        if (hitB) { first = c0 + 64 + __builtin_ctzll(hitB); break; }
    }

    // exactness fallback: nothing matched in [0, covered) -> scan the rest.
    if (first == IDX_INF) {
        // loop above exited with c0 = smallest multiple of 128 >= L;
        // coverage so far is [0, c0).
        for (; c0 < M_BOX; c0 += 128) {
            const int mA = c0 + lane;
            const int mB = mA + 64;
            const bool vA = (mA < M_BOX);
            const bool vB = (mB < M_BOX);
            const int iA = (kbase + (vA ? mA : 0)) * 3;
            const int iB = (kbase + (vB ? mB : 0)) * 3;
            const float2 aA = dp2[iA];
            const float2 bA = dp2[iA + 1];
            const float2 aB = dp2[iB];
            const float2 bB = dp2[iB + 1];

            const float areaA = (bA.x - aA.x) * (bA.y - aA.y);
            const float interA = fmaxf(fminf(px2, bA.x) - fmaxf(px1, aA.x), 0.0f)
                               * fmaxf(fminf(py2, bA.y) - fmaxf(py1, aA.y), 0.0f);
            const float denA = a1 + areaA - interA + EPS_IOU;

            const float areaB = (bB.x - aB.x) * (bB.y - aB.y);
            const float interB = fmaxf(fminf(px2, bB.x) - fmaxf(px1, aB.x), 0.0f)
                               * fmaxf(fminf(py2, bB.y) - fmaxf(py1, aB.y), 0.0f);
            const float denB = a1 + areaB - interB + EPS_IOU;

            const unsigned long long hitA = __ballot(vA && (interA > 0.5f * denA));
            const unsigned long long hitB = __ballot(vB && (interB > 0.5f * denB));
            if (hitA) { first = c0 + __builtin_ctzll(hitA); break; }
            if (hitB) { first = c0 + 64 + __builtin_ctzll(hitB); break; }
        }
    }

    // entropy of the matched class-conf row (identical math to ref)
    const float inv_n  = 1.0f / (float)C_CLS;
    const float max_en = -(float)C_CLS * (inv_n * logf(inv_n));  // == log(C)
    float u = 0.0f, mt = 0.0f;
    if (first != IDX_INF) {  // wave-uniform branch
        mt = 1.0f;
        const float* row = dconfs + (kbase + first) * (long)C_CLS;
        float local = 0.0f;
        {
            const float v = row[lane];
            local -= v * logf(v);
        }
        if (lane < C_CLS - 64) {
            const float v = row[64 + lane];
            local -= v * logf(v);
        }
        #pragma unroll
        for (int off = 32; off > 0; off >>= 1)
            local += __shfl_xor(local, off, 64);
        u = 1.0f - local / max_en;
    }

    if (lane == 0) {
        s_u[k] = u * mt;
        s_m[k] = mt;
    }
    __syncthreads();

    if (threadIdx.x == 0) {
        float cnt = 0.0f, su = 0.0f;
        #pragma unroll
        for (int kk = 0; kk < K_PASS; ++kk) { su += s_u[kk]; cnt += s_m[kk]; }
        out[n] = (cnt > 0.0f) ? (su / fmaxf(cnt, 1.0f)) : __builtin_nanf("");
    }
}

extern "C" void kernel_launch(void* const* d_in, const int* in_sizes, int n_in,
                              void* d_out, int out_size, void* d_ws, size_t ws_size,
                              hipStream_t stream) {
    const float* pred   = (const float*)d_in[0];   // [N,6]
    const float* dpreds = (const float*)d_in[1];   // [K,M,6]
    const float* dconfs = (const float*)d_in[2];   // [K,M,C]
    float* out = (float*)d_out;                    // [N]

    ue_cls_kernel<<<dim3(N_PRED), dim3(BLK_T), 0, stream>>>(pred, dpreds, dconfs, out);
}